// Round 6
// baseline (362.985 us; speedup 1.0000x reference)
//
#include <hip/hip_runtime.h>

#define T_SEQ 512
#define INPUT 14
#define HID 8
#define TC 16
#define NCHUNK (T_SEQ / TC)
#define BN_EPS 1e-5f

__device__ __forceinline__ float fast_exp2(float x) { return __builtin_amdgcn_exp2f(x); }
__device__ __forceinline__ float fast_rcp(float x)  { return __builtin_amdgcn_rcpf(x); }

// ds_swizzle fallback for xor16 (LDS pipe)
template <int IMM>
__device__ __forceinline__ float swz(float v) {
    return __int_as_float(__builtin_amdgcn_ds_swizzle(__float_as_int(v), IMM));
}

// DPP cross-lane ops (VALU pipe)
#define DPP_XOR1 0xB1   // quad_perm [1,0,3,2]
#define DPP_XOR2 0x4E   // quad_perm [2,3,0,1]
#define DPP_XOR3 0x1B   // quad_perm [3,2,1,0]
#define DPP_XOR7 0x141  // row_half_mirror: lane ^= 7 within 8-group
#define DPP_XOR8 0x128  // row_ror:8: lane ^= 8 within 16-row
template <int CTRL>
__device__ __forceinline__ float dpp(float v) {
    return __int_as_float(__builtin_amdgcn_update_dpp(
        0, __float_as_int(v), CTRL, 0xF, 0xF, true));
}

// xor16 without the DS pipe: v_permlane16_swap_b32 with src==dst gives, per lane,
// the unordered pair {v, v[lane^16]} in {r[0], r[1]}; r[0]^r[1]^v recovers
// v[lane^16] bit-exactly for EITHER row-pairing polarity.
// Verified bit-exact on HW in round 5 (absmax 0.0).
#if defined(__has_builtin)
#if __has_builtin(__builtin_amdgcn_permlane16_swap)
#define HAVE_PLSWAP 1
#endif
#endif

__device__ __forceinline__ float xor16(float v) {
#ifdef HAVE_PLSWAP
    int a = __float_as_int(v);
    auto r = __builtin_amdgcn_permlane16_swap(a, a, false, false);
    return __int_as_float(((int)r[0]) ^ ((int)r[1]) ^ a);
#else
    return swz<0x401F>(v);
#endif
}

// Produce hx[m] = value of h at lane (g ^ m), m in [0,8): 7 DPP movs, depth 2.
__device__ __forceinline__ void butterfly8(float h, float (&hx)[8]) {
    hx[0] = h;
    hx[1] = dpp<DPP_XOR1>(h);
    hx[2] = dpp<DPP_XOR2>(h);
    hx[3] = dpp<DPP_XOR3>(h);
    float h7 = dpp<DPP_XOR7>(h);
    hx[7] = h7;
    hx[4] = dpp<DPP_XOR3>(h7);   // xor 3 of xor 7 = xor 4
    hx[5] = dpp<DPP_XOR2>(h7);   // xor 5
    hx[6] = dpp<DPP_XOR1>(h7);   // xor 6
}

// Block: 256 threads = 4 waves; each wave handles 2 batch elements (32 lanes each).
// Lane g in [0,32): unit = g&7, type = g>>3 (0=i,1=f,2=g,3=o) -- PyTorch gate order.
// Cross-lane: DPP for xor1..8, permlane16_swap for xor16 -- zero DS ops on the
// recurrent chain. Scalar fp32 FMAs (v_pk_fma_f32 has no rate advantage on gfx950;
// packing regressed r5 by +20us busy).
__global__ __launch_bounds__(256, 2)
void lstm_forex_kernel(const float* __restrict__ x,
                       const float* __restrict__ Wih1, const float* __restrict__ Whh1,
                       const float* __restrict__ bih1, const float* __restrict__ bhh1,
                       const float* __restrict__ Wih2, const float* __restrict__ Whh2,
                       const float* __restrict__ bih2, const float* __restrict__ bhh2,
                       const float* __restrict__ bn_gamma, const float* __restrict__ bn_beta,
                       const float* __restrict__ bn_mean, const float* __restrict__ bn_var,
                       const float* __restrict__ w1p, const float* __restrict__ b1p,
                       const float* __restrict__ w2p, const float* __restrict__ b2p,
                       float* __restrict__ out)
{
    __shared__ float xbuf[4][2][TC][16];   // [wave][elem][t][14 padded to 16]

    const int tid  = threadIdx.x;
    const int wave = tid >> 6;
    const int lane = tid & 63;
    const int grp  = lane >> 5;          // which of the wave's 2 batch elements
    const int g    = lane & 31;          // gate row index
    const int u    = g & 7;
    const int type = g >> 3;
    const bool b0  = (type & 1) != 0;
    const bool b1  = (type & 2) != 0;

    const int b = blockIdx.x * 8 + wave * 2 + grp;

    // ---- per-lane weight rows; recurrent mats pre-permuted for XOR butterfly ----
    float wi1[INPUT], wh1p[8], wi2p[8], wh2p[8];
#pragma unroll
    for (int k = 0; k < INPUT; ++k) wi1[k] = Wih1[g * INPUT + k];
#pragma unroll
    for (int m = 0; m < 8; ++m) {
        int j = u ^ m;
        wh1p[m] = Whh1[g * HID + j];
        wi2p[m] = Wih2[g * HID + j];
        wh2p[m] = Whh2[g * HID + j];
    }
    const float bsum1 = bih1[g] + bhh1[g];
    const float bsum2 = bih2[g] + bhh2[g];

    // branch-free activation constants: sigmoid for i,f,o; tanh for g (type==2)
    const float actScale = (type == 2) ? -2.885390082f : -1.4426950408f;
    const float actMul   = (type == 2) ? 2.f : 1.f;
    const float actAdd   = (type == 2) ? -1.f : 0.f;

    // ---- x staging: 448 dwords per wave-chunk (2 elems * 16 t * 14), 7 per lane ----
    const float* gptr[7];
    int loff[7];
#pragma unroll
    for (int it = 0; it < 7; ++it) {
        int d   = it * 64 + lane;       // coalesced flat dword index within wave-chunk
        int es  = d / 224;              // which elem
        int idx = d - es * 224;         // dword within elem's 16x14 chunk
        int tr  = idx / 14;
        int k   = idx - tr * 14;
        int bb  = blockIdx.x * 8 + wave * 2 + es;
        gptr[it] = x + (size_t)bb * (T_SEQ * INPUT) + idx;
        loff[it] = es * (TC * 16) + tr * 16 + k;   // padded LDS layout
    }

    float hx1[8], hx2[8];               // butterfly images of h1, h2
    float c1 = 0.f, c2 = 0.f;
#pragma unroll
    for (int m = 0; m < 8; ++m) { hx1[m] = 0.f; hx2[m] = 0.f; }

    // prefetch chunk 0
    float st[7];
#pragma unroll
    for (int it = 0; it < 7; ++it) { st[it] = *gptr[it]; gptr[it] += TC * INPUT; }

    float (*xw)[TC][16] = xbuf[wave];

    for (int c = 0; c < NCHUNK; ++c) {
        // stage chunk c into LDS (in-order DS per wave makes this visible to reads below)
#pragma unroll
        for (int it = 0; it < 7; ++it) ((float*)xw)[loff[it]] = st[it];
        // prefetch chunk c+1 while computing chunk c
        if (c + 1 < NCHUNK) {
#pragma unroll
            for (int it = 0; it < 7; ++it) { st[it] = *gptr[it]; gptr[it] += TC * INPUT; }
        }
        __builtin_amdgcn_wave_barrier();

#pragma unroll
        for (int t = 0; t < TC; ++t) {
            const float* xrow = &xw[grp][t][0];
            float4 xa = *(const float4*)(xrow + 0);
            float4 xb = *(const float4*)(xrow + 4);
            float4 xc = *(const float4*)(xrow + 8);
            float2 xd = *(const float2*)(xrow + 12);

            // ---- layer 1 gate pre-activation (x part off critical path) ----
            float a0 = bsum1, a1 = 0.f;
            a0 = fmaf(xa.x, wi1[0], a0);  a1 = fmaf(xa.y, wi1[1], a1);
            a0 = fmaf(xa.z, wi1[2], a0);  a1 = fmaf(xa.w, wi1[3], a1);
            a0 = fmaf(xb.x, wi1[4], a0);  a1 = fmaf(xb.y, wi1[5], a1);
            a0 = fmaf(xb.z, wi1[6], a0);  a1 = fmaf(xb.w, wi1[7], a1);
            a0 = fmaf(xc.x, wi1[8], a0);  a1 = fmaf(xc.y, wi1[9], a1);
            a0 = fmaf(xc.z, wi1[10], a0); a1 = fmaf(xc.w, wi1[11], a1);
            a0 = fmaf(xd.x, wi1[12], a0); a1 = fmaf(xd.y, wi1[13], a1);
            // layer-2 recurrent part (uses h2 of previous step -- off chain)
            float q0 = bsum2, q1 = 0.f;
#pragma unroll
            for (int m = 0; m < 8; m += 2) {
                q0 = fmaf(hx2[m],     wh2p[m],     q0);
                q1 = fmaf(hx2[m + 1], wh2p[m + 1], q1);
            }
            // layer-1 recurrent butterfly dot
#pragma unroll
            for (int m = 0; m < 8; m += 2) {
                a0 = fmaf(hx1[m],     wh1p[m],     a0);
                a1 = fmaf(hx1[m + 1], wh1p[m + 1], a1);
            }
            float acc = a0 + a1;

            // own-type activation (sigmoid for i,f,o; tanh for g)
            float v0 = fmaf(fast_rcp(1.f + fast_exp2(actScale * acc)), actMul, actAdd);
            // gate exchange: all VALU (DPP + permlane16_swap)
            float v2 = xor16(v0);              // xor 16
            float v1 = dpp<DPP_XOR8>(v0);      // xor 8
            float v3 = dpp<DPP_XOR8>(v2);      // xor 24
            // P = sigmoid(i)*tanh(g), F = sigmoid(f), O = sigmoid(o)
            float P = b0 ? v1 * v3 : v0 * v2;
            float A = b0 ? v0 : v1;
            float Bq = b0 ? v2 : v3;
            float F = b1 ? Bq : A;
            float O = b1 ? A : Bq;
            c1 = fmaf(F, c1, P);
            float th1 = fmaf(fast_rcp(1.f + fast_exp2(-2.885390082f * c1)), 2.f, -1.f);
            float h1u = O * th1;               // every lane holds h1[own unit]
            butterfly8(h1u, hx1);              // 7 DPP movs (reused next step too)

            // ---- layer 2 ----
            float p0 = q0, p1 = q1;
#pragma unroll
            for (int m = 0; m < 8; m += 2) {
                p0 = fmaf(hx1[m],     wi2p[m],     p0);
                p1 = fmaf(hx1[m + 1], wi2p[m + 1], p1);
            }
            float acc2 = p0 + p1;

            float u0 = fmaf(fast_rcp(1.f + fast_exp2(actScale * acc2)), actMul, actAdd);
            float u2 = xor16(u0);
            float u1 = dpp<DPP_XOR8>(u0);
            float u3 = dpp<DPP_XOR8>(u2);
            float P2 = b0 ? u1 * u3 : u0 * u2;
            float A2 = b0 ? u0 : u1;
            float B2 = b0 ? u2 : u3;
            float F2 = b1 ? B2 : A2;
            float O2 = b1 ? A2 : B2;
            c2 = fmaf(F2, c2, P2);
            float th2 = fmaf(fast_rcp(1.f + fast_exp2(-2.885390082f * c2)), 2.f, -1.f);
            float h2u = O2 * th2;
            butterfly8(h2u, hx2);
        }
    }

    // ---- BN (eval) + MLP head, one lane per batch element ----
    // At lane g==0 (u==0): hx2[m] = h2[m].
    if (g == 0) {
        float nd[HID];
#pragma unroll
        for (int j = 0; j < HID; ++j) {
            float inv = 1.f / sqrtf(bn_var[j] + BN_EPS);
            nd[j] = bn_gamma[j] * (hx2[j] - bn_mean[j]) * inv + bn_beta[j];
        }
        float acc = b2p[0];
#pragma unroll
        for (int m = 0; m < 4; ++m) {
            float s = b1p[m];
#pragma unroll
            for (int j = 0; j < HID; ++j) s = fmaf(nd[j], w1p[m * HID + j], s);
            s = fmaxf(s, 0.f);
            acc = fmaf(s, w2p[m], acc);
        }
        out[b] = acc;
    }
}

extern "C" void kernel_launch(void* const* d_in, const int* in_sizes, int n_in,
                              void* d_out, int out_size, void* d_ws, size_t ws_size,
                              hipStream_t stream) {
    const float* x        = (const float*)d_in[0];
    const float* Wih1     = (const float*)d_in[1];
    const float* Whh1     = (const float*)d_in[2];
    const float* bih1     = (const float*)d_in[3];
    const float* bhh1     = (const float*)d_in[4];
    const float* Wih2     = (const float*)d_in[5];
    const float* Whh2     = (const float*)d_in[6];
    const float* bih2     = (const float*)d_in[7];
    const float* bhh2     = (const float*)d_in[8];
    const float* bn_gamma = (const float*)d_in[9];
    const float* bn_beta  = (const float*)d_in[10];
    const float* bn_mean  = (const float*)d_in[11];
    const float* bn_var   = (const float*)d_in[12];
    const float* w1p      = (const float*)d_in[13];
    const float* b1p      = (const float*)d_in[14];
    const float* w2p      = (const float*)d_in[15];
    const float* b2p      = (const float*)d_in[16];
    float* out = (float*)d_out;

    const int B = in_sizes[0] / (T_SEQ * INPUT);   // 4096
    dim3 grid(B / 8), block(256);
    hipLaunchKernelGGL(lstm_forex_kernel, grid, block, 0, stream,
                       x, Wih1, Whh1, bih1, bhh1, Wih2, Whh2, bih2, bhh2,
                       bn_gamma, bn_beta, bn_mean, bn_var, w1p, b1p, w2p, b2p, out);
}

// Round 7
// 336.552 us; speedup vs baseline: 1.0785x; 1.0785x over previous
//
#include <hip/hip_runtime.h>

#define T_SEQ 512
#define INPUT 14
#define HID 8
#define TC 16
#define NCHUNK (T_SEQ / TC)
#define BN_EPS 1e-5f

__device__ __forceinline__ float fast_exp2(float x) { return __builtin_amdgcn_exp2f(x); }
__device__ __forceinline__ float fast_rcp(float x)  { return __builtin_amdgcn_rcpf(x); }

// ds_swizzle (LDS crossbar): BitMode imm = xor<<10 | or<<5 | and
template <int IMM>
__device__ __forceinline__ float swz(float v) {
    return __int_as_float(__builtin_amdgcn_ds_swizzle(__float_as_int(v), IMM));
}

// DPP cross-lane ops (VALU pipe)
#define DPP_XOR1 0xB1   // quad_perm [1,0,3,2] : lane ^= 1 within quad
#define DPP_XOR2 0x4E   // quad_perm [2,3,0,1] : lane ^= 2
#define DPP_XOR3 0x1B   // quad_perm [3,2,1,0] : lane ^= 3
#define DPP_XOR8 0x128  // row_ror:8 : lane ^= 8 within 16-row
template <int CTRL>
__device__ __forceinline__ float dpp(float v) {
    return __int_as_float(__builtin_amdgcn_update_dpp(
        0, __float_as_int(v), CTRL, 0xF, 0xF, true));
}

// UNIT-MAJOR layout: lane(within 32) = unit*4 + type.
// Butterfly images of h over unit bits (lane bits 2..4): hx[m] = h at lane^(4m).
// xor4/16/20 via swizzle (has slack: consumed after 14 off-chain x-FMAs),
// xor8/12/24/28 via ror:8 DPP of {h, x4, x16, x20}.
__device__ __forceinline__ void butterfly8u(float h, float (&hx)[8]) {
    hx[0] = h;
    float x4  = swz<0x101F>(h);    // xor 4
    float x16 = swz<0x401F>(h);    // xor 16
    float x20 = swz<0x501F>(h);    // xor 20
    hx[1] = x4;
    hx[2] = dpp<DPP_XOR8>(h);      // xor 8
    hx[3] = dpp<DPP_XOR8>(x4);     // xor 12
    hx[4] = x16;
    hx[5] = x20;
    hx[6] = dpp<DPP_XOR8>(x16);    // xor 24
    hx[7] = dpp<DPP_XOR8>(x20);    // xor 28
}

// Block: 256 threads = 4 waves; each wave handles 2 batch elements (32 lanes each).
// Within 32 lanes: unit = (l5>>2)&7, type = l5&3 (0=i,1=f,2=g,3=o -- PyTorch order),
// weight row = type*8 + unit. Gate exchange = 3 quad_perm DPPs (chain depth 1).
__global__ __launch_bounds__(256, 2)
void lstm_forex_kernel(const float* __restrict__ x,
                       const float* __restrict__ Wih1, const float* __restrict__ Whh1,
                       const float* __restrict__ bih1, const float* __restrict__ bhh1,
                       const float* __restrict__ Wih2, const float* __restrict__ Whh2,
                       const float* __restrict__ bih2, const float* __restrict__ bhh2,
                       const float* __restrict__ bn_gamma, const float* __restrict__ bn_beta,
                       const float* __restrict__ bn_mean, const float* __restrict__ bn_var,
                       const float* __restrict__ w1p, const float* __restrict__ b1p,
                       const float* __restrict__ w2p, const float* __restrict__ b2p,
                       float* __restrict__ out)
{
    __shared__ float xbuf[4][2][TC][16];   // [wave][elem][t][14 padded to 16]

    const int tid  = threadIdx.x;
    const int wave = tid >> 6;
    const int lane = tid & 63;
    const int grp  = lane >> 5;          // which of the wave's 2 batch elements
    const int l5   = lane & 31;
    const int u    = (l5 >> 2) & 7;      // unit
    const int type = l5 & 3;             // gate type
    const int row  = type * 8 + u;       // weight row (PyTorch i,f,g,o blocks)
    const bool b0  = (type & 1) != 0;
    const bool b1  = (type & 2) != 0;

    const int b = blockIdx.x * 8 + wave * 2 + grp;

    // ---- per-lane weight rows; recurrent mats pre-permuted for XOR butterfly ----
    float wi1[INPUT], wh1p[8], wi2p[8], wh2p[8];
#pragma unroll
    for (int k = 0; k < INPUT; ++k) wi1[k] = Wih1[row * INPUT + k];
#pragma unroll
    for (int m = 0; m < 8; ++m) {
        int j = u ^ m;
        wh1p[m] = Whh1[row * HID + j];
        wi2p[m] = Wih2[row * HID + j];
        wh2p[m] = Whh2[row * HID + j];
    }
    const float bsum1 = bih1[row] + bhh1[row];
    const float bsum2 = bih2[row] + bhh2[row];

    // branch-free activation constants: sigmoid for i,f,o; tanh for g (type==2)
    const float actScale = (type == 2) ? -2.885390082f : -1.4426950408f;
    const float actMul   = (type == 2) ? 2.f : 1.f;
    const float actAdd   = (type == 2) ? -1.f : 0.f;

    // ---- x staging: 448 dwords per wave-chunk (2 elems * 16 t * 14), 7 per lane ----
    const float* gptr[7];
    int loff[7];
#pragma unroll
    for (int it = 0; it < 7; ++it) {
        int d   = it * 64 + lane;       // coalesced flat dword index within wave-chunk
        int es  = d / 224;              // which elem
        int idx = d - es * 224;         // dword within elem's 16x14 chunk
        int tr  = idx / 14;
        int k   = idx - tr * 14;
        int bb  = blockIdx.x * 8 + wave * 2 + es;
        gptr[it] = x + (size_t)bb * (T_SEQ * INPUT) + idx;
        loff[it] = es * (TC * 16) + tr * 16 + k;   // padded LDS layout
    }

    float hx1[8], hx2[8];               // butterfly images of h1, h2
    float c1 = 0.f, c2 = 0.f;
#pragma unroll
    for (int m = 0; m < 8; ++m) { hx1[m] = 0.f; hx2[m] = 0.f; }

    // prefetch chunk 0
    float st[7];
#pragma unroll
    for (int it = 0; it < 7; ++it) { st[it] = *gptr[it]; gptr[it] += TC * INPUT; }

    float (*xw)[TC][16] = xbuf[wave];

    for (int c = 0; c < NCHUNK; ++c) {
        // stage chunk c into LDS (in-order DS per wave makes this visible to reads below)
#pragma unroll
        for (int it = 0; it < 7; ++it) ((float*)xw)[loff[it]] = st[it];
        // prefetch chunk c+1 while computing chunk c
        if (c + 1 < NCHUNK) {
#pragma unroll
            for (int it = 0; it < 7; ++it) { st[it] = *gptr[it]; gptr[it] += TC * INPUT; }
        }
        __builtin_amdgcn_wave_barrier();

#pragma unroll
        for (int t = 0; t < TC; ++t) {
            const float* xrow = &xw[grp][t][0];
            float4 xa = *(const float4*)(xrow + 0);
            float4 xb = *(const float4*)(xrow + 4);
            float4 xc = *(const float4*)(xrow + 8);
            float2 xd = *(const float2*)(xrow + 12);

            // ---- layer 1 gate pre-activation (x part off critical path; its issue
            //      slack also hides the butterfly swizzle latency from last step) ----
            float a0 = bsum1, a1 = 0.f;
            a0 = fmaf(xa.x, wi1[0], a0);  a1 = fmaf(xa.y, wi1[1], a1);
            a0 = fmaf(xa.z, wi1[2], a0);  a1 = fmaf(xa.w, wi1[3], a1);
            a0 = fmaf(xb.x, wi1[4], a0);  a1 = fmaf(xb.y, wi1[5], a1);
            a0 = fmaf(xb.z, wi1[6], a0);  a1 = fmaf(xb.w, wi1[7], a1);
            a0 = fmaf(xc.x, wi1[8], a0);  a1 = fmaf(xc.y, wi1[9], a1);
            a0 = fmaf(xc.z, wi1[10], a0); a1 = fmaf(xc.w, wi1[11], a1);
            a0 = fmaf(xd.x, wi1[12], a0); a1 = fmaf(xd.y, wi1[13], a1);
            // layer-2 recurrent part (uses h2 of previous step -- off chain)
            float q0 = bsum2, q1 = 0.f;
#pragma unroll
            for (int m = 0; m < 8; m += 2) {
                q0 = fmaf(hx2[m],     wh2p[m],     q0);
                q1 = fmaf(hx2[m + 1], wh2p[m + 1], q1);
            }
            // layer-1 recurrent butterfly dot
#pragma unroll
            for (int m = 0; m < 8; m += 2) {
                a0 = fmaf(hx1[m],     wh1p[m],     a0);
                a1 = fmaf(hx1[m + 1], wh1p[m + 1], a1);
            }
            float acc = a0 + a1;

            // own-type activation (sigmoid for i,f,o; tanh for g)
            float v0 = fmaf(fast_rcp(1.f + fast_exp2(actScale * acc)), actMul, actAdd);
            // gate exchange within the quad: 3 parallel quad_perm DPPs, depth 1
            float v1 = dpp<DPP_XOR1>(v0);      // type ^ 1
            float v2 = dpp<DPP_XOR2>(v0);      // type ^ 2
            float v3 = dpp<DPP_XOR3>(v0);      // type ^ 3
            // P = sigmoid(i)*tanh(g), F = sigmoid(f), O = sigmoid(o)
            float P = b0 ? v1 * v3 : v0 * v2;
            float A = b0 ? v0 : v1;
            float Bq = b0 ? v2 : v3;
            float F = b1 ? Bq : A;
            float O = b1 ? A : Bq;
            c1 = fmaf(F, c1, P);
            float th1 = fmaf(fast_rcp(1.f + fast_exp2(-2.885390082f * c1)), 2.f, -1.f);
            float h1u = O * th1;               // every lane holds h1[own unit]
            butterfly8u(h1u, hx1);             // 3 swz + 4 dpp

            // ---- layer 2 ----
            float p0 = q0, p1 = q1;
#pragma unroll
            for (int m = 0; m < 8; m += 2) {
                p0 = fmaf(hx1[m],     wi2p[m],     p0);
                p1 = fmaf(hx1[m + 1], wi2p[m + 1], p1);
            }
            float acc2 = p0 + p1;

            float u0 = fmaf(fast_rcp(1.f + fast_exp2(actScale * acc2)), actMul, actAdd);
            float u1 = dpp<DPP_XOR1>(u0);
            float u2 = dpp<DPP_XOR2>(u0);
            float u3 = dpp<DPP_XOR3>(u0);
            float P2 = b0 ? u1 * u3 : u0 * u2;
            float A2 = b0 ? u0 : u1;
            float B2 = b0 ? u2 : u3;
            float F2 = b1 ? B2 : A2;
            float O2 = b1 ? A2 : B2;
            c2 = fmaf(F2, c2, P2);
            float th2 = fmaf(fast_rcp(1.f + fast_exp2(-2.885390082f * c2)), 2.f, -1.f);
            float h2u = O2 * th2;
            butterfly8u(h2u, hx2);
        }
    }

    // ---- BN (eval) + MLP head, one lane per batch element ----
    // At l5==0 (u==0, type==0): hx2[m] = h2 at lane 4m = h2[m].
    if (l5 == 0) {
        float nd[HID];
#pragma unroll
        for (int j = 0; j < HID; ++j) {
            float inv = 1.f / sqrtf(bn_var[j] + BN_EPS);
            nd[j] = bn_gamma[j] * (hx2[j] - bn_mean[j]) * inv + bn_beta[j];
        }
        float acc = b2p[0];
#pragma unroll
        for (int m = 0; m < 4; ++m) {
            float s = b1p[m];
#pragma unroll
            for (int j = 0; j < HID; ++j) s = fmaf(nd[j], w1p[m * HID + j], s);
            s = fmaxf(s, 0.f);
            acc = fmaf(s, w2p[m], acc);
        }
        out[b] = acc;
    }
}

extern "C" void kernel_launch(void* const* d_in, const int* in_sizes, int n_in,
                              void* d_out, int out_size, void* d_ws, size_t ws_size,
                              hipStream_t stream) {
    const float* x        = (const float*)d_in[0];
    const float* Wih1     = (const float*)d_in[1];
    const float* Whh1     = (const float*)d_in[2];
    const float* bih1     = (const float*)d_in[3];
    const float* bhh1     = (const float*)d_in[4];
    const float* Wih2     = (const float*)d_in[5];
    const float* Whh2     = (const float*)d_in[6];
    const float* bih2     = (const float*)d_in[7];
    const float* bhh2     = (const float*)d_in[8];
    const float* bn_gamma = (const float*)d_in[9];
    const float* bn_beta  = (const float*)d_in[10];
    const float* bn_mean  = (const float*)d_in[11];
    const float* bn_var   = (const float*)d_in[12];
    const float* w1p      = (const float*)d_in[13];
    const float* b1p      = (const float*)d_in[14];
    const float* w2p      = (const float*)d_in[15];
    const float* b2p      = (const float*)d_in[16];
    float* out = (float*)d_out;

    const int B = in_sizes[0] / (T_SEQ * INPUT);   // 4096
    dim3 grid(B / 8), block(256);
    hipLaunchKernelGGL(lstm_forex_kernel, grid, block, 0, stream,
                       x, Wih1, Whh1, bih1, bhh1, Wih2, Whh2, bih2, bhh2,
                       bn_gamma, bn_beta, bn_mean, bn_var, w1p, b1p, w2p, b2p, out);
}